// Round 1
// baseline (5930.757 us; speedup 1.0000x reference)
//
#include <hip/hip_runtime.h>

#define N_NODES 50000
#define N_EDGES 600000
#define DIM     128
#define HMLP    256
#define NCLS    32
#define NGRAPH  512
#define NLAYER  3
#define BN_EPS  1e-5f

// ---------------- GEMM: C = op(A[M,K] @ W[K,Nc] + bias), row-major ----------------
__global__ __launch_bounds__(256) void gemm_kernel(
    const float* __restrict__ A, const float* __restrict__ W,
    const float* __restrict__ bias, float* __restrict__ C,
    int M, int K, int Nc, int do_relu)
{
    __shared__ float As[64][17];
    __shared__ float Ws[16][65];
    int tx = threadIdx.x & 15, ty = threadIdx.x >> 4;
    int row0 = blockIdx.x * 64, col0 = blockIdx.y * 64;
    float acc[4][4] = {};
    for (int k0 = 0; k0 < K; k0 += 16) {
#pragma unroll
        for (int i = 0; i < 4; ++i) {
            int idx = (int)threadIdx.x + i * 256;
            int r = idx >> 4, c = idx & 15;
            int gr = row0 + r;
            As[r][c] = (gr < M) ? A[(size_t)gr * K + k0 + c] : 0.f;
        }
#pragma unroll
        for (int i = 0; i < 4; ++i) {
            int idx = (int)threadIdx.x + i * 256;
            int r = idx >> 6, c = idx & 63;
            int gc = col0 + c;
            Ws[r][c] = (gc < Nc) ? W[(size_t)(k0 + r) * Nc + gc] : 0.f;
        }
        __syncthreads();
#pragma unroll
        for (int kk = 0; kk < 16; ++kk) {
            float a[4], b[4];
#pragma unroll
            for (int i = 0; i < 4; ++i) a[i] = As[ty * 4 + i][kk];
#pragma unroll
            for (int j = 0; j < 4; ++j) b[j] = Ws[kk][tx * 4 + j];
#pragma unroll
            for (int i = 0; i < 4; ++i)
#pragma unroll
                for (int j = 0; j < 4; ++j)
                    acc[i][j] = fmaf(a[i], b[j], acc[i][j]);
        }
        __syncthreads();
    }
#pragma unroll
    for (int i = 0; i < 4; ++i) {
        int gr = row0 + ty * 4 + i;
        if (gr >= M) continue;
#pragma unroll
        for (int j = 0; j < 4; ++j) {
            int gc = col0 + tx * 4 + j;
            if (gc >= Nc) continue;
            float v = acc[i][j] + (bias ? bias[gc] : 0.f);
            if (do_relu) v = fmaxf(v, 0.f);
            C[(size_t)gr * Nc + gc] = v;
        }
    }
}

// ---------------- degree count per relation (by col) ----------------
__global__ void deg_kernel(const int* __restrict__ ei, const int* __restrict__ ea,
                           float* __restrict__ deg)
{
    int e = blockIdx.x * blockDim.x + threadIdx.x;
    if (e >= N_EDGES) return;
    int c = ei[N_EDGES + e];
#pragma unroll
    for (int r = 0; r < 3; ++r)
        if (ea[e * 3 + r] == 1) atomicAdd(&deg[r * N_NODES + c], 1.f);
}

__global__ void dinv_kernel(float* __restrict__ deg)
{
    int t = blockIdx.x * blockDim.x + threadIdx.x;
    if (t >= 3 * N_NODES) return;
    float d = deg[t];
    deg[t] = (d > 0.f) ? rsqrtf(d) : 0.f;
}

__global__ void norm_kernel(const int* __restrict__ ei, const int* __restrict__ ea,
                            const float* __restrict__ dinv, float* __restrict__ normw)
{
    int e = blockIdx.x * blockDim.x + threadIdx.x;
    int r = blockIdx.y;
    if (e >= N_EDGES) return;
    float w = (ea[e * 3 + r] == 1) ? 1.f : 0.f;
    int rr = ei[e], cc = ei[N_EDGES + e];
    normw[(size_t)r * N_EDGES + e] = dinv[r * N_NODES + rr] * dinv[r * N_NODES + cc] * w;
}

// ---------------- edge scatter: A[col] += norm * H[row] ----------------
__global__ void scatter_kernel(const float* __restrict__ H, const float* __restrict__ normw,
                               const int* __restrict__ ei, float* __restrict__ Acc)
{
    long t = (long)blockIdx.x * blockDim.x + threadIdx.x;
    int e = (int)(t >> 5);
    if (e >= N_EDGES) return;
    int g = (int)(t & 31);
    float nw = normw[e];
    if (nw == 0.f) return;
    int r = ei[e], c = ei[N_EDGES + e];
    const float4 h = *(const float4*)(H + (size_t)r * DIM + g * 4);
    float* dst = Acc + (size_t)c * DIM + g * 4;
    atomicAdd(dst + 0, nw * h.x);
    atomicAdd(dst + 1, nw * h.y);
    atomicAdd(dst + 2, nw * h.z);
    atomicAdd(dst + 3, nw * h.w);
}

// ---------------- Y += relu(A + bias) ----------------
__global__ void combine_kernel(float* __restrict__ Y, const float* __restrict__ Acc,
                               const float* __restrict__ bias)
{
    long t = (long)blockIdx.x * blockDim.x + threadIdx.x;
    if (t >= (long)N_NODES * DIM) return;
    int ch = (int)(t & (DIM - 1));
    Y[t] += fmaxf(Acc[t] + bias[ch], 0.f);
}

// ---------------- BN stats (sum, sumsq per channel) ----------------
__global__ void bn_stats_kernel(const float* __restrict__ Y, float* __restrict__ stats)
{
    int ch = threadIdx.x;  // 128 threads
    float s = 0.f, ss = 0.f;
    for (int r = blockIdx.x; r < N_NODES; r += gridDim.x) {
        float v = Y[(size_t)r * DIM + ch];
        s += v; ss += v * v;
    }
    atomicAdd(&stats[ch], s);
    atomicAdd(&stats[DIM + ch], ss);
}

__global__ void bn_apply_kernel(const float* __restrict__ Y, const float* __restrict__ stats,
                                const float* __restrict__ gamma, const float* __restrict__ beta,
                                float* __restrict__ X)
{
    long t = (long)blockIdx.x * blockDim.x + threadIdx.x;
    if (t >= (long)N_NODES * DIM) return;
    int ch = (int)(t & (DIM - 1));
    const float invN = 1.f / (float)N_NODES;
    float mu = stats[ch] * invN;
    float var = stats[DIM + ch] * invN - mu * mu;
    float inv = rsqrtf(var + BN_EPS);
    float v = (Y[t] - mu) * inv * gamma[ch] + beta[ch];
    X[t] = fmaxf(v, 0.f);
}

// ---------------- global add pool ----------------
__global__ void pool_kernel(const float* __restrict__ X, const int* __restrict__ batch,
                            float* __restrict__ pooled)
{
    long t = (long)blockIdx.x * blockDim.x + threadIdx.x;
    if (t >= (long)N_NODES * DIM) return;
    int n = (int)(t >> 7), ch = (int)(t & (DIM - 1));
    atomicAdd(&pooled[(size_t)batch[n] * DIM + ch], X[t]);
}

// ---------------- build concat [X | pooled[batch]] ----------------
__global__ void concat_kernel(const float* __restrict__ X, const float* __restrict__ pooled,
                              const int* __restrict__ batch, float* __restrict__ Cat)
{
    long t = (long)blockIdx.x * blockDim.x + threadIdx.x;
    if (t >= (long)N_NODES * 2 * DIM) return;
    int n = (int)(t >> 8), c = (int)(t & (2 * DIM - 1));
    float v = (c < DIM) ? X[(size_t)n * DIM + c]
                        : pooled[(size_t)batch[n] * DIM + (c - DIM)];
    Cat[t] = v;
}

extern "C" void kernel_launch(void* const* d_in, const int* in_sizes, int n_in,
                              void* d_out, int out_size, void* d_ws, size_t ws_size,
                              hipStream_t stream) {
    (void)in_sizes; (void)n_in; (void)out_size; (void)ws_size;
    const float* x_in = (const float*)d_in[0];
    const int* edge_index = (const int*)d_in[1];
    const int* edge_attr  = (const int*)d_in[2];
    const int* batch      = (const int*)d_in[3];
    const float* Wrel[3] = { (const float*)d_in[4], (const float*)d_in[6], (const float*)d_in[8] };
    const float* brel[3] = { (const float*)d_in[5], (const float*)d_in[7], (const float*)d_in[9] };
    const float* W_i   = (const float*)d_in[10];
    const float* b_i   = (const float*)d_in[11];
    const float* gamma = (const float*)d_in[12];
    const float* beta  = (const float*)d_in[13];
    const float* W_fc1 = (const float*)d_in[14];
    const float* b_fc1 = (const float*)d_in[15];
    const float* W_fc2 = (const float*)d_in[16];
    const float* b_fc2 = (const float*)d_in[17];
    float* out = (float*)d_out;

    float* ws = (float*)d_ws;
    float* normw  = ws;                                  // 3*E
    float* deg    = normw + (size_t)3 * N_EDGES;         // 3*N
    float* stats  = deg + (size_t)3 * N_NODES;           // 2*D
    float* pooled = stats + 2 * DIM;                     // G*D
    float* Xbuf   = pooled + (size_t)NGRAPH * DIM;       // N*D
    float* Ybuf   = Xbuf + (size_t)N_NODES * DIM;        // N*D
    float* Hbuf   = Ybuf + (size_t)N_NODES * DIM;        // N*D
    float* Abuf   = Hbuf + (size_t)N_NODES * DIM;        // N*D
    // concat reuses Hbuf..Abuf (2*N*D contiguous); hidden reuses Xbuf..Ybuf.

    const long ND = (long)N_NODES * DIM;
    dim3 blk256(256);
    dim3 grid_nd((unsigned)((ND + 255) / 256));
    dim3 grid_edges((unsigned)((N_EDGES + 255) / 256));

    // ---- edge norm precompute (layer-invariant) ----
    hipMemsetAsync(deg, 0, (size_t)3 * N_NODES * sizeof(float), stream);
    deg_kernel<<<grid_edges, blk256, 0, stream>>>(edge_index, edge_attr, deg);
    dinv_kernel<<<dim3((3 * N_NODES + 255) / 256), blk256, 0, stream>>>(deg);
    norm_kernel<<<dim3((N_EDGES + 255) / 256, 3), blk256, 0, stream>>>(edge_index, edge_attr, deg, normw);

    const float* xcur = x_in;
    for (int l = 0; l < NLAYER; ++l) {
        // identity branch: Y = relu(x @ W_i + b_i)
        gemm_kernel<<<dim3((N_NODES + 63) / 64, (DIM + 63) / 64), blk256, 0, stream>>>(
            xcur, W_i + (size_t)l * DIM * DIM, b_i + (size_t)l * DIM, Ybuf, N_NODES, DIM, DIM, 1);
        for (int r = 0; r < 3; ++r) {
            gemm_kernel<<<dim3((N_NODES + 63) / 64, (DIM + 63) / 64), blk256, 0, stream>>>(
                xcur, Wrel[r] + (size_t)l * DIM * DIM, nullptr, Hbuf, N_NODES, DIM, DIM, 0);
            hipMemsetAsync(Abuf, 0, (size_t)ND * sizeof(float), stream);
            scatter_kernel<<<dim3((unsigned)(((long)N_EDGES * 32 + 255) / 256)), blk256, 0, stream>>>(
                Hbuf, normw + (size_t)r * N_EDGES, edge_index, Abuf);
            combine_kernel<<<grid_nd, blk256, 0, stream>>>(Ybuf, Abuf, brel[r] + (size_t)l * DIM);
        }
        // BatchNorm + ReLU
        hipMemsetAsync(stats, 0, 2 * DIM * sizeof(float), stream);
        bn_stats_kernel<<<dim3(256), dim3(DIM), 0, stream>>>(Ybuf, stats);
        bn_apply_kernel<<<grid_nd, blk256, 0, stream>>>(Ybuf, stats, gamma + (size_t)l * DIM,
                                                        beta + (size_t)l * DIM, Xbuf);
        xcur = Xbuf;
    }

    // ---- pool + concat + MLP ----
    hipMemsetAsync(pooled, 0, (size_t)NGRAPH * DIM * sizeof(float), stream);
    pool_kernel<<<grid_nd, blk256, 0, stream>>>(Xbuf, batch, pooled);
    concat_kernel<<<dim3((unsigned)((2 * ND + 255) / 256)), blk256, 0, stream>>>(Xbuf, pooled, batch, Hbuf);
    // hidden = relu(concat @ W_fc1 + b_fc1), hidden lives in Xbuf..Ybuf (N x 256)
    gemm_kernel<<<dim3((N_NODES + 63) / 64, (HMLP + 63) / 64), blk256, 0, stream>>>(
        Hbuf, W_fc1, b_fc1, Xbuf, N_NODES, 2 * DIM, HMLP, 1);
    // out = hidden @ W_fc2 + b_fc2
    gemm_kernel<<<dim3((N_NODES + 63) / 64, (NCLS + 63) / 64), blk256, 0, stream>>>(
        Xbuf, W_fc2, b_fc2, out, N_NODES, HMLP, NCLS, 0);
}

// Round 2
// 1787.249 us; speedup vs baseline: 3.3184x; 3.3184x over previous
//
#include <hip/hip_runtime.h>

#define N_NODES 50000
#define N_EDGES 600000
#define DIM     128
#define HMLP    256
#define NCLS    32
#define NGRAPH  512
#define NLAYER  3
#define BN_EPS  1e-5f

// ---------------- GEMM: C = op(A[M,K] @ W[K,Nc] + bias), row-major ----------------
__global__ __launch_bounds__(256) void gemm_kernel(
    const float* __restrict__ A, const float* __restrict__ W,
    const float* __restrict__ bias, float* __restrict__ C,
    int M, int K, int Nc, int do_relu)
{
    __shared__ float As[64][17];
    __shared__ float Ws[16][65];
    int tx = threadIdx.x & 15, ty = threadIdx.x >> 4;
    int row0 = blockIdx.x * 64, col0 = blockIdx.y * 64;
    float acc[4][4] = {};
    for (int k0 = 0; k0 < K; k0 += 16) {
#pragma unroll
        for (int i = 0; i < 4; ++i) {
            int idx = (int)threadIdx.x + i * 256;
            int r = idx >> 4, c = idx & 15;
            int gr = row0 + r;
            As[r][c] = (gr < M) ? A[(size_t)gr * K + k0 + c] : 0.f;
        }
#pragma unroll
        for (int i = 0; i < 4; ++i) {
            int idx = (int)threadIdx.x + i * 256;
            int r = idx >> 6, c = idx & 63;
            int gc = col0 + c;
            Ws[r][c] = (gc < Nc) ? W[(size_t)(k0 + r) * Nc + gc] : 0.f;
        }
        __syncthreads();
#pragma unroll
        for (int kk = 0; kk < 16; ++kk) {
            float a[4], b[4];
#pragma unroll
            for (int i = 0; i < 4; ++i) a[i] = As[ty * 4 + i][kk];
#pragma unroll
            for (int j = 0; j < 4; ++j) b[j] = Ws[kk][tx * 4 + j];
#pragma unroll
            for (int i = 0; i < 4; ++i)
#pragma unroll
                for (int j = 0; j < 4; ++j)
                    acc[i][j] = fmaf(a[i], b[j], acc[i][j]);
        }
        __syncthreads();
    }
#pragma unroll
    for (int i = 0; i < 4; ++i) {
        int gr = row0 + ty * 4 + i;
        if (gr >= M) continue;
#pragma unroll
        for (int j = 0; j < 4; ++j) {
            int gc = col0 + tx * 4 + j;
            if (gc >= Nc) continue;
            float v = acc[i][j] + (bias ? bias[gc] : 0.f);
            if (do_relu) v = fmaxf(v, 0.f);
            C[(size_t)gr * Nc + gc] = v;
        }
    }
}

// ---------------- degree counts: per-relation (float) + all-edge (int) ----------------
__global__ void deg_kernel(const int* __restrict__ ei, const int* __restrict__ ea,
                           float* __restrict__ degs, int* __restrict__ dega)
{
    int e = blockIdx.x * blockDim.x + threadIdx.x;
    if (e >= N_EDGES) return;
    int c = ei[N_EDGES + e];
    atomicAdd(&dega[c], 1);
    if (ea[e * 3 + 0] == 1) atomicAdd(&degs[0 * N_NODES + c], 1.f);
    if (ea[e * 3 + 1] == 1) atomicAdd(&degs[1 * N_NODES + c], 1.f);
    if (ea[e * 3 + 2] == 1) atomicAdd(&degs[2 * N_NODES + c], 1.f);
}

__global__ void dinv_kernel(float* __restrict__ degs)
{
    int t = blockIdx.x * blockDim.x + threadIdx.x;
    if (t >= 3 * N_NODES) return;
    float d = degs[t];
    degs[t] = (d > 0.f) ? rsqrtf(d) : 0.f;
}

// ---------------- exclusive scan of dega -> rowptr, cursor (single block) ----------------
__global__ __launch_bounds__(1024) void scan_kernel(const int* __restrict__ dega,
                                                    int* __restrict__ rowptr,
                                                    int* __restrict__ cursor)
{
    __shared__ int sh[1024];
    const int PER = (N_NODES + 1023) / 1024;
    int t = threadIdx.x;
    int start = t * PER;
    int local = 0;
    for (int k = 0; k < PER; ++k) {
        int i = start + k;
        if (i < N_NODES) {
            rowptr[i] = local;         // exclusive within segment (temp)
            local += dega[i];
        }
    }
    sh[t] = local;
    __syncthreads();
    for (int off = 1; off < 1024; off <<= 1) {
        int v = (t >= off) ? sh[t - off] : 0;
        __syncthreads();
        sh[t] += v;
        __syncthreads();
    }
    int excl = sh[t] - local;
    for (int k = 0; k < PER; ++k) {
        int i = start + k;
        if (i < N_NODES) {
            int v = rowptr[i] + excl;
            rowptr[i] = v;
            cursor[i] = v;
        }
    }
    if (t == 1023) rowptr[N_NODES] = sh[1023];
}

// ---------------- fill CSR slots with src id + 3 relation norms ----------------
__global__ void fill_kernel(const int* __restrict__ ei, const int* __restrict__ ea,
                            const float* __restrict__ dinv, int* __restrict__ cursor,
                            int* __restrict__ csr_src, float* __restrict__ n0,
                            float* __restrict__ n1, float* __restrict__ n2)
{
    int e = blockIdx.x * blockDim.x + threadIdx.x;
    if (e >= N_EDGES) return;
    int r = ei[e], c = ei[N_EDGES + e];
    int slot = atomicAdd(&cursor[c], 1);
    csr_src[slot] = r;
    n0[slot] = (ea[e * 3 + 0] == 1) ? dinv[0 * N_NODES + r] * dinv[0 * N_NODES + c] : 0.f;
    n1[slot] = (ea[e * 3 + 1] == 1) ? dinv[1 * N_NODES + r] * dinv[1 * N_NODES + c] : 0.f;
    n2[slot] = (ea[e * 3 + 2] == 1) ? dinv[2 * N_NODES + r] * dinv[2 * N_NODES + c] : 0.f;
}

// ---------------- gather: Y[n] += sum_rel relu( sum_e norm*H[src,rel] + b_rel ) ----------------
__global__ __launch_bounds__(128) void gather_kernel(
    const float* __restrict__ H, const int* __restrict__ rowptr,
    const int* __restrict__ csr_src, const float* __restrict__ n0,
    const float* __restrict__ n1, const float* __restrict__ n2,
    const float* __restrict__ bs, const float* __restrict__ bd,
    const float* __restrict__ bt, float* __restrict__ Y)
{
    int n = blockIdx.x, c = threadIdx.x;
    int p0 = rowptr[n], p1 = rowptr[n + 1];
    float a0 = 0.f, a1 = 0.f, a2 = 0.f;
    for (int p = p0; p < p1; ++p) {
        int s = csr_src[p];
        const float* h = H + (size_t)s * 384;
        float w0 = n0[p], w1 = n1[p], w2 = n2[p];
        if (w0 != 0.f) a0 = fmaf(w0, h[c], a0);
        if (w1 != 0.f) a1 = fmaf(w1, h[128 + c], a1);
        if (w2 != 0.f) a2 = fmaf(w2, h[256 + c], a2);
    }
    float v = fmaxf(a0 + bs[c], 0.f) + fmaxf(a1 + bd[c], 0.f) + fmaxf(a2 + bt[c], 0.f);
    Y[(size_t)n * DIM + c] += v;
}

// ---------------- BN stats (sum, sumsq per channel) ----------------
__global__ void bn_stats_kernel(const float* __restrict__ Y, float* __restrict__ stats)
{
    int ch = threadIdx.x;  // 128 threads
    float s = 0.f, ss = 0.f;
    for (int r = blockIdx.x; r < N_NODES; r += gridDim.x) {
        float v = Y[(size_t)r * DIM + ch];
        s += v; ss += v * v;
    }
    atomicAdd(&stats[ch], s);
    atomicAdd(&stats[DIM + ch], ss);
}

__global__ void bn_apply_kernel(const float* __restrict__ Y, const float* __restrict__ stats,
                                const float* __restrict__ gamma, const float* __restrict__ beta,
                                float* __restrict__ X)
{
    long t = (long)blockIdx.x * blockDim.x + threadIdx.x;
    if (t >= (long)N_NODES * DIM) return;
    int ch = (int)(t & (DIM - 1));
    const float invN = 1.f / (float)N_NODES;
    float mu = stats[ch] * invN;
    float var = stats[DIM + ch] * invN - mu * mu;
    float inv = rsqrtf(var + BN_EPS);
    float v = (Y[t] - mu) * inv * gamma[ch] + beta[ch];
    X[t] = fmaxf(v, 0.f);
}

// ---------------- global add pool ----------------
__global__ void pool_kernel(const float* __restrict__ X, const int* __restrict__ batch,
                            float* __restrict__ pooled)
{
    long t = (long)blockIdx.x * blockDim.x + threadIdx.x;
    if (t >= (long)N_NODES * DIM) return;
    int n = (int)(t >> 7), ch = (int)(t & (DIM - 1));
    atomicAdd(&pooled[(size_t)batch[n] * DIM + ch], X[t]);
}

// ---------------- build concat [X | pooled[batch]] ----------------
__global__ void concat_kernel(const float* __restrict__ X, const float* __restrict__ pooled,
                              const int* __restrict__ batch, float* __restrict__ Cat)
{
    long t = (long)blockIdx.x * blockDim.x + threadIdx.x;
    if (t >= (long)N_NODES * 2 * DIM) return;
    int n = (int)(t >> 8), c = (int)(t & (2 * DIM - 1));
    float v = (c < DIM) ? X[(size_t)n * DIM + c]
                        : pooled[(size_t)batch[n] * DIM + (c - DIM)];
    Cat[t] = v;
}

// ---------------- build concatenated relation weights [L][K=128][384] ----------------
__global__ void wcat_kernel(const float* __restrict__ Ws, const float* __restrict__ Wd,
                            const float* __restrict__ Wt, float* __restrict__ Wcat)
{
    int idx = blockIdx.x * blockDim.x + threadIdx.x;
    if (idx >= NLAYER * DIM * 384) return;
    int l = idx / (DIM * 384);
    int rem = idx - l * DIM * 384;
    int k = rem / 384;
    int j = rem - k * 384;
    int rel = j >> 7, jj = j & 127;
    const float* src = (rel == 0) ? Ws : (rel == 1) ? Wd : Wt;
    Wcat[idx] = src[(size_t)l * DIM * DIM + (size_t)k * DIM + jj];
}

extern "C" void kernel_launch(void* const* d_in, const int* in_sizes, int n_in,
                              void* d_out, int out_size, void* d_ws, size_t ws_size,
                              hipStream_t stream) {
    (void)in_sizes; (void)n_in; (void)out_size; (void)ws_size;
    const float* x_in = (const float*)d_in[0];
    const int* edge_index = (const int*)d_in[1];
    const int* edge_attr  = (const int*)d_in[2];
    const int* batch      = (const int*)d_in[3];
    const float* W_s   = (const float*)d_in[4];
    const float* b_s   = (const float*)d_in[5];
    const float* W_d   = (const float*)d_in[6];
    const float* b_d   = (const float*)d_in[7];
    const float* W_t   = (const float*)d_in[8];
    const float* b_t   = (const float*)d_in[9];
    const float* W_i   = (const float*)d_in[10];
    const float* b_i   = (const float*)d_in[11];
    const float* gamma = (const float*)d_in[12];
    const float* beta  = (const float*)d_in[13];
    const float* W_fc1 = (const float*)d_in[14];
    const float* b_fc1 = (const float*)d_in[15];
    const float* W_fc2 = (const float*)d_in[16];
    const float* b_fc2 = (const float*)d_in[17];
    float* out = (float*)d_out;

    // ---- workspace layout (floats) ----
    float* ws = (float*)d_ws;
    float* dinv   = ws;                                   // 3*N (deg counts, then rsqrt in place)
    int*   dega   = (int*)(dinv + (size_t)3 * N_NODES);   // N
    int*   rowptr = dega + N_NODES;                       // N+1
    int*   cursor = rowptr + N_NODES + 1;                 // N
    int*   csr_src= cursor + N_NODES;                     // E
    float* n0     = (float*)(csr_src + N_EDGES);          // E
    float* n1     = n0 + N_EDGES;                         // E
    float* n2     = n1 + N_EDGES;                         // E
    float* stats  = n2 + N_EDGES;                         // 2*D
    float* pooled = stats + 2 * DIM;                      // G*D
    float* Wcat   = pooled + (size_t)NGRAPH * DIM;        // 3*128*384
    float* Hbuf   = Wcat + (size_t)NLAYER * DIM * 384;    // N*384
    float* Xbuf   = Hbuf + (size_t)N_NODES * 384;         // N*128
    float* Ybuf   = Xbuf + (size_t)N_NODES * DIM;         // N*128  (X..Y contiguous: reused as hidden N*256)

    const long ND = (long)N_NODES * DIM;
    dim3 blk256(256);
    dim3 grid_nd((unsigned)((ND + 255) / 256));
    dim3 grid_edges((unsigned)((N_EDGES + 255) / 256));

    // ---- CSR + norm precompute (layer-invariant) ----
    hipMemsetAsync(dinv, 0, ((size_t)3 * N_NODES + N_NODES) * sizeof(float), stream);
    deg_kernel<<<grid_edges, blk256, 0, stream>>>(edge_index, edge_attr, dinv, dega);
    dinv_kernel<<<dim3((3 * N_NODES + 255) / 256), blk256, 0, stream>>>(dinv);
    scan_kernel<<<dim3(1), dim3(1024), 0, stream>>>(dega, rowptr, cursor);
    fill_kernel<<<grid_edges, blk256, 0, stream>>>(edge_index, edge_attr, dinv, cursor,
                                                   csr_src, n0, n1, n2);
    wcat_kernel<<<dim3((NLAYER * DIM * 384 + 255) / 256), blk256, 0, stream>>>(W_s, W_d, W_t, Wcat);

    const float* xcur = x_in;
    for (int l = 0; l < NLAYER; ++l) {
        // identity branch directly into Y: Y = relu(x @ W_i + b_i)
        gemm_kernel<<<dim3((N_NODES + 63) / 64, 2), blk256, 0, stream>>>(
            xcur, W_i + (size_t)l * DIM * DIM, b_i + (size_t)l * DIM, Ybuf, N_NODES, DIM, DIM, 1);
        // all three relation transforms in one GEMM: H[N,384] = x @ Wcat_l
        gemm_kernel<<<dim3((N_NODES + 63) / 64, 6), blk256, 0, stream>>>(
            xcur, Wcat + (size_t)l * DIM * 384, nullptr, Hbuf, N_NODES, DIM, 384, 0);
        // gather all relations + bias + relu, accumulate into Y
        gather_kernel<<<dim3(N_NODES), dim3(128), 0, stream>>>(
            Hbuf, rowptr, csr_src, n0, n1, n2,
            b_s + (size_t)l * DIM, b_d + (size_t)l * DIM, b_t + (size_t)l * DIM, Ybuf);
        // BatchNorm + ReLU
        hipMemsetAsync(stats, 0, 2 * DIM * sizeof(float), stream);
        bn_stats_kernel<<<dim3(256), dim3(DIM), 0, stream>>>(Ybuf, stats);
        bn_apply_kernel<<<grid_nd, blk256, 0, stream>>>(Ybuf, stats, gamma + (size_t)l * DIM,
                                                        beta + (size_t)l * DIM, Xbuf);
        xcur = Xbuf;
    }

    // ---- pool + concat + MLP ----
    hipMemsetAsync(pooled, 0, (size_t)NGRAPH * DIM * sizeof(float), stream);
    pool_kernel<<<grid_nd, blk256, 0, stream>>>(Xbuf, batch, pooled);
    // concat lives in Hbuf (N x 256 <= N x 384)
    concat_kernel<<<dim3((unsigned)((2 * ND + 255) / 256)), blk256, 0, stream>>>(Xbuf, pooled, batch, Hbuf);
    // hidden = relu(concat @ W_fc1 + b_fc1) -> Xbuf..Ybuf region (N x 256)
    gemm_kernel<<<dim3((N_NODES + 63) / 64, 4), blk256, 0, stream>>>(
        Hbuf, W_fc1, b_fc1, Xbuf, N_NODES, 2 * DIM, HMLP, 1);
    // out = hidden @ W_fc2 + b_fc2
    gemm_kernel<<<dim3((N_NODES + 63) / 64, 1), blk256, 0, stream>>>(
        Xbuf, W_fc2, b_fc2, out, N_NODES, HMLP, NCLS, 0);
}

// Round 4
// 936.188 us; speedup vs baseline: 6.3350x; 1.9091x over previous
//
#include <hip/hip_runtime.h>
#include <hip/hip_bf16.h>

#define N_NODES 50000
#define N_EDGES 600000
#define DIM     128
#define HMLP    256
#define NCLS    32
#define NGRAPH  512
#define NLAYER  3
#define BN_EPS  1e-5f
#define NBLK_SCAN ((N_NODES + 255) / 256)

typedef unsigned short ushort_t;
typedef __attribute__((ext_vector_type(8))) short short8v;
typedef __attribute__((ext_vector_type(4))) float f32x4;

#define MODE_LAYER 0
#define MODE_BF16R 1
#define MODE_F32   2

__device__ __forceinline__ ushort_t f2b(float v) {
    __hip_bfloat16 h = __float2bfloat16(v);
    return *reinterpret_cast<ushort_t*>(&h);
}
__device__ __forceinline__ float b2f(ushort_t u) {
    __hip_bfloat16 h = *reinterpret_cast<__hip_bfloat16*>(&u);
    return __bfloat162float(h);
}

// ============ bf16 MFMA GEMM: C = A[M,K] @ BT[Nc,K]^T, 128x128 tile, 4 waves ============
__global__ __launch_bounds__(256) void mgemm_kernel(
    const ushort_t* __restrict__ A,   // [M][K] bf16
    const ushort_t* __restrict__ BT,  // [Nc][K] bf16 (B transposed)
    const float* __restrict__ bias,
    float* __restrict__ Cf,
    ushort_t* __restrict__ Cb,
    int M, int K, int mode, int ncmask, int ldc)
{
    __shared__ ushort_t As[128 * 128];
    __shared__ ushort_t Bs[128 * 128];
    const int tid = threadIdx.x, lane = tid & 63, wid = tid >> 6;
    const int wm = wid >> 1, wn = wid & 1;
    const int row0 = blockIdx.x * 128, col0 = blockIdx.y * 128;
    const int fq = lane >> 4, fr = lane & 15;

    f32x4 acc[4][4] = {};

    for (int k0 = 0; k0 < K; k0 += 128) {
#pragma unroll
        for (int j = 0; j < 8; ++j) {
            int chunk = wid * 8 + j;         // 0..31, wave-uniform
            int r = chunk * 4 + fq;          // LDS row this lane feeds
            int s = fr;                      // linear 16B slot
            int sw = s ^ (r & 7);            // inverse-swizzled source slot
            int gr = row0 + r; if (gr >= M) gr = M - 1;
            const ushort_t* srcA = A + (size_t)gr * K + k0 + (sw << 3);
            __builtin_amdgcn_global_load_lds(
                (const __attribute__((address_space(1))) unsigned int*)srcA,
                (__attribute__((address_space(3))) unsigned int*)((char*)As + chunk * 1024),
                16, 0, 0);
            const ushort_t* srcB = BT + (size_t)(col0 + r) * K + k0 + (sw << 3);
            __builtin_amdgcn_global_load_lds(
                (const __attribute__((address_space(1))) unsigned int*)srcB,
                (__attribute__((address_space(3))) unsigned int*)((char*)Bs + chunk * 1024),
                16, 0, 0);
        }
        __syncthreads();

#pragma unroll
        for (int kk = 0; kk < 4; ++kk) {
            int slot = ((kk * 4 + fq) ^ (lane & 7)) << 4;  // swizzled byte slot
            short8v a[4], b[4];
#pragma unroll
            for (int mf = 0; mf < 4; ++mf) {
                int ra = wm * 64 + mf * 16 + fr;
                a[mf] = *(const short8v*)((const char*)As + ra * 256 + slot);
                int rb = wn * 64 + mf * 16 + fr;
                b[mf] = *(const short8v*)((const char*)Bs + rb * 256 + slot);
            }
#pragma unroll
            for (int mf = 0; mf < 4; ++mf)
#pragma unroll
                for (int nf = 0; nf < 4; ++nf)
                    acc[mf][nf] = __builtin_amdgcn_mfma_f32_16x16x32_bf16(
                        a[mf], b[nf], acc[mf][nf], 0, 0, 0);
        }
        __syncthreads();
    }

    // epilogue: C[row=(fq*4+j)][col=fr] per 16x16 fragment
#pragma unroll
    for (int mf = 0; mf < 4; ++mf) {
        int rowb = row0 + wm * 64 + mf * 16 + fq * 4;
#pragma unroll
        for (int nf = 0; nf < 4; ++nf) {
            int col = col0 + wn * 64 + nf * 16 + fr;
            f32x4 v = acc[mf][nf];
#pragma unroll
            for (int j = 0; j < 4; ++j) {
                int r = rowb + j;
                if (r >= M) continue;
                float val = v[j];
                if (mode == MODE_LAYER) {
                    if (col < 128) Cf[(size_t)r * 128 + col] = fmaxf(val + bias[col], 0.f);
                    else           Cb[(size_t)r * 384 + (col - 128)] = f2b(val);
                } else if (mode == MODE_BF16R) {
                    Cb[(size_t)r * ldc + col] = f2b(fmaxf(val + bias[col], 0.f));
                } else {
                    if (col < ncmask) Cf[(size_t)r * ldc + col] = val + bias[col];
                }
            }
        }
    }
}

// ============ weight prep: transpose + bf16 ============
__global__ void wprep_kernel(const float* __restrict__ W_s, const float* __restrict__ W_d,
                             const float* __restrict__ W_t, const float* __restrict__ W_i,
                             const float* __restrict__ W_fc1, const float* __restrict__ W_fc2,
                             ushort_t* __restrict__ WTl, ushort_t* __restrict__ WT1,
                             ushort_t* __restrict__ WT2)
{
    const int SZ_L = NLAYER * 512 * 128, SZ_1 = 256 * 256, SZ_2 = 128 * 256;
    int idx = blockIdx.x * 256 + threadIdx.x;
    if (idx < SZ_L) {
        int l = idx / (512 * 128);
        int rem = idx - l * 512 * 128;
        int n = rem >> 7, k = rem & 127;
        float v;
        if (n < 128) v = W_i[((size_t)l * 128 + k) * 128 + n];
        else {
            int rel = (n - 128) >> 7, nn = (n - 128) & 127;
            const float* W = rel == 0 ? W_s : rel == 1 ? W_d : W_t;
            v = W[((size_t)l * 128 + k) * 128 + nn];
        }
        WTl[idx] = f2b(v);
    } else if (idx < SZ_L + SZ_1) {
        int j = idx - SZ_L;
        int n = j >> 8, k = j & 255;
        WT1[j] = f2b(W_fc1[(size_t)k * 256 + n]);
    } else if (idx < SZ_L + SZ_1 + SZ_2) {
        int j = idx - SZ_L - SZ_1;
        int n = j >> 8, k = j & 255;
        WT2[j] = f2b(n < 32 ? W_fc2[(size_t)k * 32 + n] : 0.f);
    }
}

__global__ void xcvt_kernel(const float* __restrict__ x, ushort_t* __restrict__ xb)
{
    long t = (long)blockIdx.x * 256 + threadIdx.x;
    if (t < (long)N_NODES * DIM) xb[t] = f2b(x[t]);
}

// ============ degree counts ============
__global__ void deg_kernel(const int* __restrict__ ei, const int* __restrict__ ea,
                           float* __restrict__ degs, int* __restrict__ dega)
{
    int e = blockIdx.x * blockDim.x + threadIdx.x;
    if (e >= N_EDGES) return;
    int c = ei[N_EDGES + e];
    atomicAdd(&dega[c], 1);
    if (ea[e * 3 + 0] == 1) atomicAdd(&degs[0 * N_NODES + c], 1.f);
    if (ea[e * 3 + 1] == 1) atomicAdd(&degs[1 * N_NODES + c], 1.f);
    if (ea[e * 3 + 2] == 1) atomicAdd(&degs[2 * N_NODES + c], 1.f);
}

__global__ void dinv_kernel(float* __restrict__ degs)
{
    int t = blockIdx.x * blockDim.x + threadIdx.x;
    if (t >= 3 * N_NODES) return;
    float d = degs[t];
    degs[t] = (d > 0.f) ? rsqrtf(d) : 0.f;
}

// ============ multi-block exclusive scan ============
__global__ void bsum_kernel(const int* __restrict__ dega, int* __restrict__ bsum)
{
    __shared__ int sh[256];
    int i = blockIdx.x * 256 + threadIdx.x;
    sh[threadIdx.x] = (i < N_NODES) ? dega[i] : 0;
    __syncthreads();
    for (int off = 128; off > 0; off >>= 1) {
        if (threadIdx.x < off) sh[threadIdx.x] += sh[threadIdx.x + off];
        __syncthreads();
    }
    if (threadIdx.x == 0) bsum[blockIdx.x] = sh[0];
}

__global__ void bscan_kernel(const int* __restrict__ bsum, int* __restrict__ boff,
                             int* __restrict__ rowptr)
{
    __shared__ int sh[256];
    int t = threadIdx.x;
    int v = (t < NBLK_SCAN) ? bsum[t] : 0;
    sh[t] = v;
    __syncthreads();
    for (int off = 1; off < 256; off <<= 1) {
        int u = (t >= off) ? sh[t - off] : 0;
        __syncthreads();
        sh[t] += u;
        __syncthreads();
    }
    if (t < NBLK_SCAN) boff[t] = sh[t] - v;
    if (t == 255) rowptr[N_NODES] = sh[255];
}

__global__ void rowptr_kernel(const int* __restrict__ dega, const int* __restrict__ boff,
                              int* __restrict__ rowptr, int* __restrict__ cursor)
{
    __shared__ int sh[256];
    int i = blockIdx.x * 256 + threadIdx.x;
    int t = threadIdx.x;
    int v = (i < N_NODES) ? dega[i] : 0;
    sh[t] = v;
    __syncthreads();
    for (int off = 1; off < 256; off <<= 1) {
        int u = (t >= off) ? sh[t - off] : 0;
        __syncthreads();
        sh[t] += u;
        __syncthreads();
    }
    if (i < N_NODES) {
        int e = boff[blockIdx.x] + sh[t] - v;
        rowptr[i] = e;
        cursor[i] = e;
    }
}

// ============ CSR fill ============
__global__ void fill_kernel(const int* __restrict__ ei, const int* __restrict__ ea,
                            const float* __restrict__ dinv, int* __restrict__ cursor,
                            int* __restrict__ csr_src, float* __restrict__ n0,
                            float* __restrict__ n1, float* __restrict__ n2)
{
    int e = blockIdx.x * blockDim.x + threadIdx.x;
    if (e >= N_EDGES) return;
    int r = ei[e], c = ei[N_EDGES + e];
    int slot = atomicAdd(&cursor[c], 1);
    csr_src[slot] = r;
    n0[slot] = (ea[e * 3 + 0] == 1) ? dinv[0 * N_NODES + r] * dinv[0 * N_NODES + c] : 0.f;
    n1[slot] = (ea[e * 3 + 1] == 1) ? dinv[1 * N_NODES + r] * dinv[1 * N_NODES + c] : 0.f;
    n2[slot] = (ea[e * 3 + 2] == 1) ? dinv[2 * N_NODES + r] * dinv[2 * N_NODES + c] : 0.f;
}

// ============ gather (bf16 H): Y[n] += sum_rel relu(sum_e norm*H[src,rel] + b_rel) ============
__global__ __launch_bounds__(128) void gather_kernel(
    const ushort_t* __restrict__ Hb, const int* __restrict__ rowptr,
    const int* __restrict__ csr_src, const float* __restrict__ n0,
    const float* __restrict__ n1, const float* __restrict__ n2,
    const float* __restrict__ bs, const float* __restrict__ bd,
    const float* __restrict__ bt, float* __restrict__ Y)
{
    int n = blockIdx.x, c = threadIdx.x;
    int p0 = rowptr[n], p1 = rowptr[n + 1];
    float a0 = 0.f, a1 = 0.f, a2 = 0.f;
    for (int p = p0; p < p1; ++p) {
        int s = csr_src[p];
        const ushort_t* h = Hb + (size_t)s * 384;
        float w0 = n0[p], w1 = n1[p], w2 = n2[p];
        if (w0 != 0.f) a0 = fmaf(w0, b2f(h[c]), a0);
        if (w1 != 0.f) a1 = fmaf(w1, b2f(h[128 + c]), a1);
        if (w2 != 0.f) a2 = fmaf(w2, b2f(h[256 + c]), a2);
    }
    float v = fmaxf(a0 + bs[c], 0.f) + fmaxf(a1 + bd[c], 0.f) + fmaxf(a2 + bt[c], 0.f);
    Y[(size_t)n * DIM + c] += v;
}

// ============ BN ============
__global__ void bn_stats_kernel(const float* __restrict__ Y, float* __restrict__ stats)
{
    int ch = threadIdx.x;  // 128 threads
    float s = 0.f, ss = 0.f;
    for (int r = blockIdx.x; r < N_NODES; r += gridDim.x) {
        float v = Y[(size_t)r * DIM + ch];
        s += v; ss += v * v;
    }
    atomicAdd(&stats[ch], s);
    atomicAdd(&stats[DIM + ch], ss);
}

__global__ void bn_apply_kernel(const float* __restrict__ Y, const float* __restrict__ stats,
                                const float* __restrict__ gamma, const float* __restrict__ beta,
                                ushort_t* __restrict__ Xb)
{
    long t = (long)blockIdx.x * blockDim.x + threadIdx.x;
    if (t >= (long)N_NODES * DIM) return;
    int ch = (int)(t & (DIM - 1));
    const float invN = 1.f / (float)N_NODES;
    float mu = stats[ch] * invN;
    float var = stats[DIM + ch] * invN - mu * mu;
    float inv = rsqrtf(var + BN_EPS);
    float v = (Y[t] - mu) * inv * gamma[ch] + beta[ch];
    Xb[t] = f2b(fmaxf(v, 0.f));
}

// ============ pool + concat ============
__global__ void pool_kernel(const ushort_t* __restrict__ Xb, const int* __restrict__ batch,
                            float* __restrict__ pooled)
{
    long t = (long)blockIdx.x * blockDim.x + threadIdx.x;
    if (t >= (long)N_NODES * DIM) return;
    int n = (int)(t >> 7), ch = (int)(t & (DIM - 1));
    atomicAdd(&pooled[(size_t)batch[n] * DIM + ch], b2f(Xb[t]));
}

__global__ void concat_kernel(const ushort_t* __restrict__ Xb, const float* __restrict__ pooled,
                              const int* __restrict__ batch, ushort_t* __restrict__ Cat)
{
    long t = (long)blockIdx.x * blockDim.x + threadIdx.x;
    if (t >= (long)N_NODES * 2 * DIM) return;
    int n = (int)(t >> 8), c = (int)(t & (2 * DIM - 1));
    Cat[t] = (c < DIM) ? Xb[(size_t)n * DIM + c]
                       : f2b(pooled[(size_t)batch[n] * DIM + (c - DIM)]);
}

extern "C" void kernel_launch(void* const* d_in, const int* in_sizes, int n_in,
                              void* d_out, int out_size, void* d_ws, size_t ws_size,
                              hipStream_t stream) {
    (void)in_sizes; (void)n_in; (void)out_size; (void)ws_size;
    const float* x_in = (const float*)d_in[0];
    const int* edge_index = (const int*)d_in[1];
    const int* edge_attr  = (const int*)d_in[2];
    const int* batch      = (const int*)d_in[3];
    const float* W_s   = (const float*)d_in[4];
    const float* b_s   = (const float*)d_in[5];
    const float* W_d   = (const float*)d_in[6];
    const float* b_d   = (const float*)d_in[7];
    const float* W_t   = (const float*)d_in[8];
    const float* b_t   = (const float*)d_in[9];
    const float* W_i   = (const float*)d_in[10];
    const float* b_i   = (const float*)d_in[11];
    const float* gamma = (const float*)d_in[12];
    const float* beta  = (const float*)d_in[13];
    const float* W_fc1 = (const float*)d_in[14];
    const float* b_fc1 = (const float*)d_in[15];
    const float* W_fc2 = (const float*)d_in[16];
    const float* b_fc2 = (const float*)d_in[17];
    float* out = (float*)d_out;

    // ---- workspace layout ----
    char* ws = (char*)d_ws;
    size_t off = 0;
    auto alloc = [&](size_t bytes) { char* p = ws + off; off += (bytes + 255) & ~(size_t)255; return p; };
    float* dinv    = (float*)alloc((size_t)3 * N_NODES * 4);
    int*   dega    = (int*)  alloc((size_t)N_NODES * 4);
    int*   rowptr  = (int*)  alloc((size_t)(N_NODES + 1) * 4);
    int*   cursor  = (int*)  alloc((size_t)N_NODES * 4);
    int*   bsum    = (int*)  alloc(256 * 4);
    int*   boff    = (int*)  alloc(256 * 4);
    int*   csr_src = (int*)  alloc((size_t)N_EDGES * 4);
    float* n0      = (float*)alloc((size_t)N_EDGES * 4);
    float* n1      = (float*)alloc((size_t)N_EDGES * 4);
    float* n2      = (float*)alloc((size_t)N_EDGES * 4);
    float* stats   = (float*)alloc(2 * DIM * 4);
    float* pooled  = (float*)alloc((size_t)NGRAPH * DIM * 4);
    ushort_t* WTl  = (ushort_t*)alloc((size_t)NLAYER * 512 * 128 * 2);
    ushort_t* WT1  = (ushort_t*)alloc((size_t)256 * 256 * 2);
    ushort_t* WT2  = (ushort_t*)alloc((size_t)128 * 256 * 2);
    ushort_t* Xb   = (ushort_t*)alloc((size_t)N_NODES * DIM * 2);
    float* Yb      = (float*)alloc((size_t)N_NODES * DIM * 4);      // reused as concat (bf16 N*256)
    ushort_t* Hb   = (ushort_t*)alloc((size_t)N_NODES * 384 * 2);   // reused as hidden (bf16 N*256)
    ushort_t* Cat    = (ushort_t*)Yb;
    ushort_t* Hidden = Hb;

    const long ND = (long)N_NODES * DIM;
    dim3 blk256(256);
    dim3 grid_nd((unsigned)((ND + 255) / 256));
    dim3 grid_edges((unsigned)((N_EDGES + 255) / 256));
    const int MB = (N_NODES + 127) / 128;   // 391 row blocks

    // ---- prep: CSR + norms + weights + x (all layer-invariant) ----
    // NOTE: alloc() rounds to 256B, so dinv and dega are NOT contiguous — zero separately.
    hipMemsetAsync(dinv, 0, (size_t)3 * N_NODES * 4, stream);
    hipMemsetAsync(dega, 0, (size_t)N_NODES * 4, stream);
    deg_kernel<<<grid_edges, blk256, 0, stream>>>(edge_index, edge_attr, dinv, dega);
    dinv_kernel<<<dim3((3 * N_NODES + 255) / 256), blk256, 0, stream>>>(dinv);
    bsum_kernel<<<dim3(NBLK_SCAN), blk256, 0, stream>>>(dega, bsum);
    bscan_kernel<<<dim3(1), blk256, 0, stream>>>(bsum, boff, rowptr);
    rowptr_kernel<<<dim3(NBLK_SCAN), blk256, 0, stream>>>(dega, boff, rowptr, cursor);
    fill_kernel<<<grid_edges, blk256, 0, stream>>>(edge_index, edge_attr, dinv, cursor,
                                                   csr_src, n0, n1, n2);
    wprep_kernel<<<dim3((NLAYER * 512 * 128 + 256 * 256 + 128 * 256 + 255) / 256), blk256, 0, stream>>>(
        W_s, W_d, W_t, W_i, W_fc1, W_fc2, WTl, WT1, WT2);
    xcvt_kernel<<<grid_nd, blk256, 0, stream>>>(x_in, Xb);

    for (int l = 0; l < NLAYER; ++l) {
        // fused [identity | s | d | t] GEMM: Y=relu(x@Wi+bi) (f32), Hb=x@[Ws|Wd|Wt] (bf16)
        mgemm_kernel<<<dim3(MB, 4), blk256, 0, stream>>>(
            Xb, WTl + (size_t)l * 512 * 128, b_i + (size_t)l * DIM,
            Yb, Hb, N_NODES, DIM, MODE_LAYER, 0, 0);
        gather_kernel<<<dim3(N_NODES), dim3(128), 0, stream>>>(
            Hb, rowptr, csr_src, n0, n1, n2,
            b_s + (size_t)l * DIM, b_d + (size_t)l * DIM, b_t + (size_t)l * DIM, Yb);
        hipMemsetAsync(stats, 0, 2 * DIM * 4, stream);
        bn_stats_kernel<<<dim3(256), dim3(DIM), 0, stream>>>(Yb, stats);
        bn_apply_kernel<<<grid_nd, blk256, 0, stream>>>(Yb, stats, gamma + (size_t)l * DIM,
                                                        beta + (size_t)l * DIM, Xb);
    }

    // ---- pool + concat + MLP ----
    hipMemsetAsync(pooled, 0, (size_t)NGRAPH * DIM * 4, stream);
    pool_kernel<<<grid_nd, blk256, 0, stream>>>(Xb, batch, pooled);
    concat_kernel<<<dim3((unsigned)((2 * ND + 255) / 256)), blk256, 0, stream>>>(Xb, pooled, batch, Cat);
    // hidden = relu(concat @ W_fc1 + b_fc1) as bf16
    mgemm_kernel<<<dim3(MB, 2), blk256, 0, stream>>>(
        Cat, WT1, b_fc1, nullptr, Hidden, N_NODES, 2 * DIM, MODE_BF16R, 0, HMLP);
    // out = hidden @ W_fc2 + b_fc2 (padded to 128 cols, store first 32)
    mgemm_kernel<<<dim3(MB, 1), blk256, 0, stream>>>(
        Hidden, WT2, b_fc2, out, nullptr, N_NODES, HMLP, MODE_F32, NCLS, NCLS);
}

// Round 5
// 722.464 us; speedup vs baseline: 8.2091x; 1.2958x over previous
//
#include <hip/hip_runtime.h>
#include <hip/hip_bf16.h>

#define N_NODES 50000
#define N_EDGES 600000
#define DIM     128
#define HMLP    256
#define NCLS    32
#define NGRAPH  512
#define NLAYER  3
#define BN_EPS  1e-5f
#define NBLK_SCAN ((N_NODES + 255) / 256)

typedef unsigned short ushort_t;
typedef unsigned int uint_t;
typedef __attribute__((ext_vector_type(8))) short short8v;
typedef __attribute__((ext_vector_type(4))) float f32x4;

#define MODE_LAYER 0
#define MODE_BF16R 1
#define MODE_F32   2

__device__ __forceinline__ ushort_t f2b(float v) {
    __hip_bfloat16 h = __float2bfloat16(v);
    return *reinterpret_cast<ushort_t*>(&h);
}
__device__ __forceinline__ float b2f(ushort_t u) {
    __hip_bfloat16 h = *reinterpret_cast<__hip_bfloat16*>(&u);
    return __bfloat162float(h);
}
__device__ __forceinline__ float blo(uint_t h) { return b2f((ushort_t)(h & 0xffffu)); }
__device__ __forceinline__ float bhi(uint_t h) { return b2f((ushort_t)(h >> 16)); }

// ============ bf16 MFMA GEMM: 128x128 tile, 4 waves, K-chunk 64 (LDS 32KB) ============
__global__ __launch_bounds__(256) void mgemm_kernel(
    const ushort_t* __restrict__ A,   // [M][K] bf16
    const ushort_t* __restrict__ BT,  // [Nc][K] bf16 (B transposed)
    const float* __restrict__ bias,
    float* __restrict__ Cf,
    ushort_t* __restrict__ Cb,
    int M, int K, int mode, int ncmask, int ldc)
{
    __shared__ ushort_t As[128 * 64];
    __shared__ ushort_t Bs[128 * 64];
    const int tid = threadIdx.x, lane = tid & 63, wid = tid >> 6;
    const int wm = wid >> 1, wn = wid & 1;
    const int row0 = blockIdx.x * 128, col0 = blockIdx.y * 128;
    const int fq = lane >> 4, fr = lane & 15;

    f32x4 acc[4][4] = {};

    for (int k0 = 0; k0 < K; k0 += 64) {
        // stage 16KB each (A,B): 4 passes x 256 threads x 16B; linear LDS dest,
        // inverse-swizzled global source (slot ^= row&7), 8 slots/128B row.
#pragma unroll
        for (int i = 0; i < 4; ++i) {
            int slotid = i * 256 + tid;         // 0..1023
            int r = slotid >> 3, sl = slotid & 7;
            int sw = sl ^ (r & 7);
            int gra = row0 + r; if (gra >= M) gra = M - 1;
            __builtin_amdgcn_global_load_lds(
                (const __attribute__((address_space(1))) unsigned int*)(A + (size_t)gra * K + k0 + (sw << 3)),
                (__attribute__((address_space(3))) unsigned int*)((char*)As + slotid * 16), 16, 0, 0);
            __builtin_amdgcn_global_load_lds(
                (const __attribute__((address_space(1))) unsigned int*)(BT + (size_t)(col0 + r) * K + k0 + (sw << 3)),
                (__attribute__((address_space(3))) unsigned int*)((char*)Bs + slotid * 16), 16, 0, 0);
        }
        __syncthreads();

#pragma unroll
        for (int kk = 0; kk < 2; ++kk) {
            short8v a[4], b[4];
#pragma unroll
            for (int mf = 0; mf < 4; ++mf) {
                int ra = wm * 64 + mf * 16 + fr;
                int sa = ((kk * 4 + fq) ^ (ra & 7)) << 4;
                a[mf] = *(const short8v*)((const char*)As + ra * 128 + sa);
                int rb = wn * 64 + mf * 16 + fr;
                int sb = ((kk * 4 + fq) ^ (rb & 7)) << 4;
                b[mf] = *(const short8v*)((const char*)Bs + rb * 128 + sb);
            }
#pragma unroll
            for (int mf = 0; mf < 4; ++mf)
#pragma unroll
                for (int nf = 0; nf < 4; ++nf)
                    acc[mf][nf] = __builtin_amdgcn_mfma_f32_16x16x32_bf16(
                        a[mf], b[nf], acc[mf][nf], 0, 0, 0);
        }
        __syncthreads();
    }

    // epilogue: C[row=(fq*4+j)][col=fr] per 16x16 fragment
#pragma unroll
    for (int mf = 0; mf < 4; ++mf) {
        int rowb = row0 + wm * 64 + mf * 16 + fq * 4;
#pragma unroll
        for (int nf = 0; nf < 4; ++nf) {
            int col = col0 + wn * 64 + nf * 16 + fr;
            f32x4 v = acc[mf][nf];
#pragma unroll
            for (int j = 0; j < 4; ++j) {
                int r = rowb + j;
                if (r >= M) continue;
                float val = v[j];
                if (mode == MODE_LAYER) {
                    // H[N][512]: [id(relu+bias) | s | d | t], all bf16
                    if (col < 128) Cb[(size_t)r * 512 + col] = f2b(fmaxf(val + bias[col], 0.f));
                    else           Cb[(size_t)r * 512 + col] = f2b(val);
                } else if (mode == MODE_BF16R) {
                    Cb[(size_t)r * ldc + col] = f2b(fmaxf(val + bias[col], 0.f));
                } else {
                    if (col < ncmask) Cf[(size_t)r * ldc + col] = val + bias[col];
                }
            }
        }
    }
}

// ============ weight prep: transpose + bf16 ============
__global__ void wprep_kernel(const float* __restrict__ W_s, const float* __restrict__ W_d,
                             const float* __restrict__ W_t, const float* __restrict__ W_i,
                             const float* __restrict__ W_fc1, const float* __restrict__ W_fc2,
                             ushort_t* __restrict__ WTl, ushort_t* __restrict__ WT1,
                             ushort_t* __restrict__ WT2)
{
    const int SZ_L = NLAYER * 512 * 128, SZ_1 = 256 * 256, SZ_2 = 128 * 256;
    int idx = blockIdx.x * 256 + threadIdx.x;
    if (idx < SZ_L) {
        int l = idx / (512 * 128);
        int rem = idx - l * 512 * 128;
        int n = rem >> 7, k = rem & 127;
        float v;
        if (n < 128) v = W_i[((size_t)l * 128 + k) * 128 + n];
        else {
            int rel = (n - 128) >> 7, nn = (n - 128) & 127;
            const float* W = rel == 0 ? W_s : rel == 1 ? W_d : W_t;
            v = W[((size_t)l * 128 + k) * 128 + nn];
        }
        WTl[idx] = f2b(v);
    } else if (idx < SZ_L + SZ_1) {
        int j = idx - SZ_L;
        int n = j >> 8, k = j & 255;
        WT1[j] = f2b(W_fc1[(size_t)k * 256 + n]);
    } else if (idx < SZ_L + SZ_1 + SZ_2) {
        int j = idx - SZ_L - SZ_1;
        int n = j >> 8, k = j & 255;
        WT2[j] = f2b(n < 32 ? W_fc2[(size_t)k * 32 + n] : 0.f);
    }
}

__global__ void xcvt_kernel(const float* __restrict__ x, ushort_t* __restrict__ xb)
{
    long t = (long)blockIdx.x * 256 + threadIdx.x;
    if (t < (long)N_NODES * DIM) xb[t] = f2b(x[t]);
}

// ============ degree counts ============
__global__ void deg_kernel(const int* __restrict__ ei, const int* __restrict__ ea,
                           float* __restrict__ degs, int* __restrict__ dega)
{
    int e = blockIdx.x * blockDim.x + threadIdx.x;
    if (e >= N_EDGES) return;
    int c = ei[N_EDGES + e];
    atomicAdd(&dega[c], 1);
    if (ea[e * 3 + 0] == 1) atomicAdd(&degs[0 * N_NODES + c], 1.f);
    if (ea[e * 3 + 1] == 1) atomicAdd(&degs[1 * N_NODES + c], 1.f);
    if (ea[e * 3 + 2] == 1) atomicAdd(&degs[2 * N_NODES + c], 1.f);
}

__global__ void dinv_kernel(float* __restrict__ degs)
{
    int t = blockIdx.x * blockDim.x + threadIdx.x;
    if (t >= 3 * N_NODES) return;
    float d = degs[t];
    degs[t] = (d > 0.f) ? rsqrtf(d) : 0.f;
}

// ============ multi-block exclusive scan ============
__global__ void bsum_kernel(const int* __restrict__ dega, int* __restrict__ bsum)
{
    __shared__ int sh[256];
    int i = blockIdx.x * 256 + threadIdx.x;
    sh[threadIdx.x] = (i < N_NODES) ? dega[i] : 0;
    __syncthreads();
    for (int off = 128; off > 0; off >>= 1) {
        if (threadIdx.x < off) sh[threadIdx.x] += sh[threadIdx.x + off];
        __syncthreads();
    }
    if (threadIdx.x == 0) bsum[blockIdx.x] = sh[0];
}

__global__ void bscan_kernel(const int* __restrict__ bsum, int* __restrict__ boff,
                             int* __restrict__ rowptr)
{
    __shared__ int sh[256];
    int t = threadIdx.x;
    int v = (t < NBLK_SCAN) ? bsum[t] : 0;
    sh[t] = v;
    __syncthreads();
    for (int off = 1; off < 256; off <<= 1) {
        int u = (t >= off) ? sh[t - off] : 0;
        __syncthreads();
        sh[t] += u;
        __syncthreads();
    }
    if (t < NBLK_SCAN) boff[t] = sh[t] - v;
    if (t == 255) rowptr[N_NODES] = sh[255];
}

__global__ void rowptr_kernel(const int* __restrict__ dega, const int* __restrict__ boff,
                              int* __restrict__ rowptr, int* __restrict__ cursor)
{
    __shared__ int sh[256];
    int i = blockIdx.x * 256 + threadIdx.x;
    int t = threadIdx.x;
    int v = (i < N_NODES) ? dega[i] : 0;
    sh[t] = v;
    __syncthreads();
    for (int off = 1; off < 256; off <<= 1) {
        int u = (t >= off) ? sh[t - off] : 0;
        __syncthreads();
        sh[t] += u;
        __syncthreads();
    }
    if (i < N_NODES) {
        int e = boff[blockIdx.x] + sh[t] - v;
        rowptr[i] = e;
        cursor[i] = e;
    }
}

// ============ CSR fill: packed per-slot metadata (n0,n1,n2,src) ============
__global__ void fill_kernel(const int* __restrict__ ei, const int* __restrict__ ea,
                            const float* __restrict__ dinv, int* __restrict__ cursor,
                            float4* __restrict__ nrm)
{
    int e = blockIdx.x * blockDim.x + threadIdx.x;
    if (e >= N_EDGES) return;
    int r = ei[e], c = ei[N_EDGES + e];
    int slot = atomicAdd(&cursor[c], 1);
    float4 m;
    m.x = (ea[e * 3 + 0] == 1) ? dinv[0 * N_NODES + r] * dinv[0 * N_NODES + c] : 0.f;
    m.y = (ea[e * 3 + 1] == 1) ? dinv[1 * N_NODES + r] * dinv[1 * N_NODES + c] : 0.f;
    m.z = (ea[e * 3 + 2] == 1) ? dinv[2 * N_NODES + r] * dinv[2 * N_NODES + c] : 0.f;
    m.w = __uint_as_float((uint_t)r);
    nrm[slot] = m;
}

// ============ gather: wave-per-node, 4-edge unroll, H[N][512] bf16 ============
// Y[n] = id[n] + sum_rel relu(sum_e norm*H[src,rel] + b_rel)
__global__ __launch_bounds__(256) void gather_kernel(
    const ushort_t* __restrict__ Hb, const int* __restrict__ rowptr,
    const float4* __restrict__ nrm,
    const float* __restrict__ bs, const float* __restrict__ bd,
    const float* __restrict__ bt, float* __restrict__ Y)
{
    int wv = threadIdx.x >> 6, lane = threadIdx.x & 63;
    int n = blockIdx.x * 4 + wv;
    if (n >= N_NODES) return;
    int p0 = rowptr[n], p1 = rowptr[n + 1];
    const char* hbase = (const char*)Hb + (lane << 2);   // 2 channels per lane
    float a0x = 0.f, a0y = 0.f, a1x = 0.f, a1y = 0.f, a2x = 0.f, a2y = 0.f;

    for (int p = p0; p < p1; p += 4) {
        float4 m[4];
        m[0] = nrm[p];
        m[1] = (p + 1 < p1) ? nrm[p + 1] : make_float4(0.f, 0.f, 0.f, 0.f);
        m[2] = (p + 2 < p1) ? nrm[p + 2] : make_float4(0.f, 0.f, 0.f, 0.f);
        m[3] = (p + 3 < p1) ? nrm[p + 3] : make_float4(0.f, 0.f, 0.f, 0.f);
        uint_t hv[4][3];
#pragma unroll
        for (int u = 0; u < 4; ++u) {
            const char* base = hbase + ((size_t)__float_as_uint(m[u].w) << 10);
            if (m[u].x != 0.f) hv[u][0] = *(const uint_t*)(base + 256);
            if (m[u].y != 0.f) hv[u][1] = *(const uint_t*)(base + 512);
            if (m[u].z != 0.f) hv[u][2] = *(const uint_t*)(base + 768);
        }
#pragma unroll
        for (int u = 0; u < 4; ++u) {
            if (m[u].x != 0.f) { a0x = fmaf(m[u].x, blo(hv[u][0]), a0x); a0y = fmaf(m[u].x, bhi(hv[u][0]), a0y); }
            if (m[u].y != 0.f) { a1x = fmaf(m[u].y, blo(hv[u][1]), a1x); a1y = fmaf(m[u].y, bhi(hv[u][1]), a1y); }
            if (m[u].z != 0.f) { a2x = fmaf(m[u].z, blo(hv[u][2]), a2x); a2y = fmaf(m[u].z, bhi(hv[u][2]), a2y); }
        }
    }

    uint_t idv = *(const uint_t*)(hbase + ((size_t)n << 10));   // id block, relu+bias applied
    float2 B0 = *(const float2*)(bs + lane * 2);
    float2 B1 = *(const float2*)(bd + lane * 2);
    float2 B2 = *(const float2*)(bt + lane * 2);
    float y0 = blo(idv) + fmaxf(a0x + B0.x, 0.f) + fmaxf(a1x + B1.x, 0.f) + fmaxf(a2x + B2.x, 0.f);
    float y1 = bhi(idv) + fmaxf(a0y + B0.y, 0.f) + fmaxf(a1y + B1.y, 0.f) + fmaxf(a2y + B2.y, 0.f);
    *(float2*)(Y + (size_t)n * DIM + lane * 2) = make_float2(y0, y1);
}

// ============ BN ============
__global__ void bn_stats_kernel(const float* __restrict__ Y, float* __restrict__ stats)
{
    int ch = threadIdx.x;  // 128 threads
    float s = 0.f, ss = 0.f;
    for (int r = blockIdx.x; r < N_NODES; r += gridDim.x) {
        float v = Y[(size_t)r * DIM + ch];
        s += v; ss += v * v;
    }
    atomicAdd(&stats[ch], s);
    atomicAdd(&stats[DIM + ch], ss);
}

__global__ void bn_apply_kernel(const float* __restrict__ Y, const float* __restrict__ stats,
                                const float* __restrict__ gamma, const float* __restrict__ beta,
                                ushort_t* __restrict__ Xb)
{
    long t = (long)blockIdx.x * blockDim.x + threadIdx.x;
    if (t >= (long)N_NODES * DIM) return;
    int ch = (int)(t & (DIM - 1));
    const float invN = 1.f / (float)N_NODES;
    float mu = stats[ch] * invN;
    float var = stats[DIM + ch] * invN - mu * mu;
    float inv = rsqrtf(var + BN_EPS);
    float v = (Y[t] - mu) * inv * gamma[ch] + beta[ch];
    Xb[t] = f2b(fmaxf(v, 0.f));
}

// ============ pool + concat ============
__global__ void pool_kernel(const ushort_t* __restrict__ Xb, const int* __restrict__ batch,
                            float* __restrict__ pooled)
{
    long t = (long)blockIdx.x * blockDim.x + threadIdx.x;
    if (t >= (long)N_NODES * DIM) return;
    int n = (int)(t >> 7), ch = (int)(t & (DIM - 1));
    atomicAdd(&pooled[(size_t)batch[n] * DIM + ch], b2f(Xb[t]));
}

__global__ void concat_kernel(const ushort_t* __restrict__ Xb, const float* __restrict__ pooled,
                              const int* __restrict__ batch, ushort_t* __restrict__ Cat)
{
    long t = (long)blockIdx.x * blockDim.x + threadIdx.x;
    if (t >= (long)N_NODES * 2 * DIM) return;
    int n = (int)(t >> 8), c = (int)(t & (2 * DIM - 1));
    Cat[t] = (c < DIM) ? Xb[(size_t)n * DIM + c]
                       : f2b(pooled[(size_t)batch[n] * DIM + (c - DIM)]);
}

extern "C" void kernel_launch(void* const* d_in, const int* in_sizes, int n_in,
                              void* d_out, int out_size, void* d_ws, size_t ws_size,
                              hipStream_t stream) {
    (void)in_sizes; (void)n_in; (void)out_size; (void)ws_size;
    const float* x_in = (const float*)d_in[0];
    const int* edge_index = (const int*)d_in[1];
    const int* edge_attr  = (const int*)d_in[2];
    const int* batch      = (const int*)d_in[3];
    const float* W_s   = (const float*)d_in[4];
    const float* b_s   = (const float*)d_in[5];
    const float* W_d   = (const float*)d_in[6];
    const float* b_d   = (const float*)d_in[7];
    const float* W_t   = (const float*)d_in[8];
    const float* b_t   = (const float*)d_in[9];
    const float* W_i   = (const float*)d_in[10];
    const float* b_i   = (const float*)d_in[11];
    const float* gamma = (const float*)d_in[12];
    const float* beta  = (const float*)d_in[13];
    const float* W_fc1 = (const float*)d_in[14];
    const float* b_fc1 = (const float*)d_in[15];
    const float* W_fc2 = (const float*)d_in[16];
    const float* b_fc2 = (const float*)d_in[17];
    float* out = (float*)d_out;

    // ---- workspace layout ----
    char* ws = (char*)d_ws;
    size_t off = 0;
    auto alloc = [&](size_t bytes) { char* p = ws + off; off += (bytes + 255) & ~(size_t)255; return p; };
    float* dinv    = (float*)alloc((size_t)3 * N_NODES * 4);
    int*   dega    = (int*)  alloc((size_t)N_NODES * 4);
    int*   rowptr  = (int*)  alloc((size_t)(N_NODES + 1) * 4);
    int*   cursor  = (int*)  alloc((size_t)N_NODES * 4);
    int*   bsum    = (int*)  alloc(256 * 4);
    int*   boff    = (int*)  alloc(256 * 4);
    float4* nrm    = (float4*)alloc((size_t)(N_EDGES + 4) * 16);
    float* stats   = (float*)alloc(2 * DIM * 4);
    float* pooled  = (float*)alloc((size_t)NGRAPH * DIM * 4);
    ushort_t* WTl  = (ushort_t*)alloc((size_t)NLAYER * 512 * 128 * 2);
    ushort_t* WT1  = (ushort_t*)alloc((size_t)256 * 256 * 2);
    ushort_t* WT2  = (ushort_t*)alloc((size_t)128 * 256 * 2);
    ushort_t* Xb   = (ushort_t*)alloc((size_t)N_NODES * DIM * 2);
    float* Yb      = (float*)alloc((size_t)N_NODES * DIM * 4);      // reused as concat (bf16 N*256)
    ushort_t* Hb   = (ushort_t*)alloc((size_t)N_NODES * 512 * 2);   // reused as hidden (bf16 N*256)
    ushort_t* Cat    = (ushort_t*)Yb;
    ushort_t* Hidden = Hb;

    const long ND = (long)N_NODES * DIM;
    dim3 blk256(256);
    dim3 grid_nd((unsigned)((ND + 255) / 256));
    dim3 grid_edges((unsigned)((N_EDGES + 255) / 256));
    const int MB = (N_NODES + 127) / 128;   // 391 row blocks

    // ---- prep: CSR + norms + weights + x (all layer-invariant) ----
    hipMemsetAsync(dinv, 0, (size_t)3 * N_NODES * 4, stream);
    hipMemsetAsync(dega, 0, (size_t)N_NODES * 4, stream);
    deg_kernel<<<grid_edges, blk256, 0, stream>>>(edge_index, edge_attr, dinv, dega);
    dinv_kernel<<<dim3((3 * N_NODES + 255) / 256), blk256, 0, stream>>>(dinv);
    bsum_kernel<<<dim3(NBLK_SCAN), blk256, 0, stream>>>(dega, bsum);
    bscan_kernel<<<dim3(1), blk256, 0, stream>>>(bsum, boff, rowptr);
    rowptr_kernel<<<dim3(NBLK_SCAN), blk256, 0, stream>>>(dega, boff, rowptr, cursor);
    fill_kernel<<<grid_edges, blk256, 0, stream>>>(edge_index, edge_attr, dinv, cursor, nrm);
    wprep_kernel<<<dim3((NLAYER * 512 * 128 + 256 * 256 + 128 * 256 + 255) / 256), blk256, 0, stream>>>(
        W_s, W_d, W_t, W_i, W_fc1, W_fc2, WTl, WT1, WT2);
    xcvt_kernel<<<grid_nd, blk256, 0, stream>>>(x_in, Xb);

    for (int l = 0; l < NLAYER; ++l) {
        // fused GEMM -> H[N][512] bf16: [relu(x@Wi+bi) | x@Ws | x@Wd | x@Wt]
        mgemm_kernel<<<dim3(MB, 4), blk256, 0, stream>>>(
            Xb, WTl + (size_t)l * 512 * 128, b_i + (size_t)l * DIM,
            nullptr, Hb, N_NODES, DIM, MODE_LAYER, 0, 512);
        gather_kernel<<<dim3((N_NODES + 3) / 4), blk256, 0, stream>>>(
            Hb, rowptr, nrm,
            b_s + (size_t)l * DIM, b_d + (size_t)l * DIM, b_t + (size_t)l * DIM, Yb);
        hipMemsetAsync(stats, 0, 2 * DIM * 4, stream);
        bn_stats_kernel<<<dim3(256), dim3(DIM), 0, stream>>>(Yb, stats);
        bn_apply_kernel<<<grid_nd, blk256, 0, stream>>>(Yb, stats, gamma + (size_t)l * DIM,
                                                        beta + (size_t)l * DIM, Xb);
    }

    // ---- pool + concat + MLP ----
    hipMemsetAsync(pooled, 0, (size_t)NGRAPH * DIM * 4, stream);
    pool_kernel<<<grid_nd, blk256, 0, stream>>>(Xb, batch, pooled);
    concat_kernel<<<dim3((unsigned)((2 * ND + 255) / 256)), blk256, 0, stream>>>(Xb, pooled, batch, Cat);
    // hidden = relu(concat @ W_fc1 + b_fc1) as bf16
    mgemm_kernel<<<dim3(MB, 2), blk256, 0, stream>>>(
        Cat, WT1, b_fc1, nullptr, Hidden, N_NODES, 2 * DIM, MODE_BF16R, 0, HMLP);
    // out = hidden @ W_fc2 + b_fc2 (padded to 128 cols, store first 32)
    mgemm_kernel<<<dim3(MB, 1), blk256, 0, stream>>>(
        Hidden, WT2, b_fc2, out, nullptr, N_NODES, HMLP, MODE_F32, NCLS, NCLS);
}